// Round 3
// baseline (2449.995 us; speedup 1.0000x reference)
//
#include <hip/hip_runtime.h>
#include <stdint.h>

#define S_LEN 2048
#define BATCH 32
#define DEMB  512
#define DRNN  256
#define G3    768   // 3*DRNN

typedef __bf16    bf16x8 __attribute__((ext_vector_type(8)));
typedef float     f32x4  __attribute__((ext_vector_type(4)));
typedef _Float16  f16x2  __attribute__((ext_vector_type(2)));
typedef _Float16  f16x8  __attribute__((ext_vector_type(8)));

__device__ __forceinline__ unsigned short f2b(float f) {    // f32 -> bf16 RNE
    unsigned int u = __builtin_bit_cast(unsigned int, f);
    unsigned int r = (u + 0x7fffu + ((u >> 16) & 1u)) >> 16;
    return (unsigned short)r;
}
__device__ __forceinline__ float sigm(float x) {
    float e = __builtin_amdgcn_exp2f(-1.4426950408889634f * x);
    return __builtin_amdgcn_rcpf(1.0f + e);
}
__device__ __forceinline__ float tanh_f(float x) {
    float e = __builtin_amdgcn_exp2f(2.8853900817779268f * x);  // e^(2x)
    return 1.0f - 2.0f * __builtin_amdgcn_rcpf(e + 1.0f);       // safe at +-inf
}
__device__ __forceinline__ float dot2acc(f16x2 w, f16x2 h, float acc) {
    return __builtin_amdgcn_fdot2(w, h, acc, false);
}
__device__ __forceinline__ f16x2 pk_f16(float lo, float hi) {
    return __builtin_bit_cast(f16x2, __builtin_amdgcn_cvt_pkrtz(lo, hi));
}

// ---------------- Kernel A: gi = x @ w_ih^T + b_ih  (both dirs, one chunk) --
// Chunk covers processing positions [p0, p0+chunk). Row m of the chunk =
// (local position p)*32 + batch b. Actual timestep t = dir ? S-1-(p0+p) : p0+p.
// gi layout: [2][chunk*32][768] f32.
__global__ __launch_bounds__(256) void gi_gemm(
    const float* __restrict__ x,
    const float* __restrict__ wih_f,
    const float* __restrict__ bih_f,
    const float* __restrict__ wih_b,
    const float* __restrict__ bih_b,
    float* __restrict__ gi,
    int p0, int chunkM)
{
    const int dir = blockIdx.z;
    const float* wih = dir ? wih_b : wih_f;
    const float* bih = dir ? bih_b : bih_f;
    float* giD = gi + (size_t)dir * (size_t)chunkM * G3;

    __shared__ __align__(16) unsigned short sA[128 * 32];
    __shared__ __align__(16) unsigned short sB[128 * 32];

    const int tid  = threadIdx.x;
    const int lane = tid & 63, wv = tid >> 6;
    const int wr = wv >> 1, wc = wv & 1;        // wave quadrant (2x2 of 64x64)
    const int lr = lane & 15, kq = lane >> 4;

    const int m0 = blockIdx.x * 128;
    const int n0 = blockIdx.y * 128;

    f32x4 acc[4][4];
    #pragma unroll
    for (int i = 0; i < 4; ++i)
        #pragma unroll
        for (int j = 0; j < 4; ++j) acc[i][j] = (f32x4){0.f, 0.f, 0.f, 0.f};

    const int srow = tid >> 3;            // 32 rows per pass, 8 threads/row
    const int scol = (tid & 7) * 4;       // 4 floats per thread

    for (int ks = 0; ks < 16; ++ks) {
        const int k0 = ks * 32;
        #pragma unroll
        for (int r = 0; r < 4; ++r) {
            const int row = srow + r * 32;
            // A: x, position-mapped row
            {
                const int m = m0 + row;
                const int p = p0 + (m >> 5), b = m & 31;
                const int t = dir ? (S_LEN - 1 - p) : p;
                const float4 v = *(const float4*)&x[((size_t)t * BATCH + b) * DEMB + k0 + scol];
                ushort4 h4; h4.x = f2b(v.x); h4.y = f2b(v.y); h4.z = f2b(v.z); h4.w = f2b(v.w);
                *(ushort4*)&sA[row * 32 + scol] = h4;
            }
            // B: w_ih rows (gate index)
            {
                const float4 v = *(const float4*)&wih[(size_t)(n0 + row) * DEMB + k0 + scol];
                ushort4 h4; h4.x = f2b(v.x); h4.y = f2b(v.y); h4.z = f2b(v.z); h4.w = f2b(v.w);
                *(ushort4*)&sB[row * 32 + scol] = h4;
            }
        }
        __syncthreads();
        bf16x8 af[4], bfr[4];
        #pragma unroll
        for (int i = 0; i < 4; ++i) {
            af[i]  = *(const bf16x8*)&sA[(wr * 64 + i * 16 + lr) * 32 + kq * 8];
            bfr[i] = *(const bf16x8*)&sB[(wc * 64 + i * 16 + lr) * 32 + kq * 8];
        }
        #pragma unroll
        for (int i = 0; i < 4; ++i)
            #pragma unroll
            for (int j = 0; j < 4; ++j)
                acc[i][j] = __builtin_amdgcn_mfma_f32_16x16x32_bf16(
                    af[i], bfr[j], acc[i][j], 0, 0, 0);
        __syncthreads();
    }
    // epilogue: C/D layout col = lane&15, row = (lane>>4)*4 + reg
    #pragma unroll
    for (int j = 0; j < 4; ++j) {
        const int g = n0 + wc * 64 + j * 16 + lr;
        const float bias = bih[g];
        #pragma unroll
        for (int i = 0; i < 4; ++i) {
            const int mbase = m0 + wr * 64 + i * 16 + kq * 4;
            #pragma unroll
            for (int r2 = 0; r2 < 4; ++r2)
                giD[(size_t)(mbase + r2) * G3 + g] = acc[i][j][r2] + bias;
        }
    }
}

// ---------------- Kernel B: the recurrence (one chunk) ----------------------
// 64 WGs: one (batch, direction) chain each. 512 threads: thread = (half, j),
// j = tid&255 owns gate rows {j, 256+j, 512+j}, half = tid>>8 owns k-half.
// w_hh held in registers as packed f16 pairs (192 VGPRs). h broadcast via LDS.
__global__ __launch_bounds__(512, 2) void gru_rec(
    const float* __restrict__ gi,               // [2][chunk*32][768]
    const float* __restrict__ whh_f,
    const float* __restrict__ bhh_f,
    const float* __restrict__ whh_b,
    const float* __restrict__ bhh_b,
    float* __restrict__ out,                    // [S*B*512] ++ [2*B*256]
    float* __restrict__ hcarry,                 // [2*B*256]
    int p0, int chunk)
{
    const int wg  = blockIdx.x;
    const int b   = wg & 31, dir = wg >> 5;
    const float* whh = dir ? whh_b : whh_f;
    const float* bhh = dir ? bhh_b : bhh_f;
    const float* giD = gi + (size_t)dir * (size_t)(chunk * BATCH) * G3;

    const int tid  = threadIdx.x;
    const int j    = tid & 255;
    const int half = tid >> 8;

    __shared__ __align__(16) _Float16 h16[DRNN];
    __shared__ float red[3][256];

    // ---- load w_hh slice into registers, f32 -> packed f16 ----
    f16x2 wreg[3][64];
    #pragma unroll
    for (int g = 0; g < 3; ++g) {
        const float2* wrow =
            (const float2*)(whh + (size_t)(g * 256 + j) * DRNN + half * 128);
        #pragma unroll
        for (int c = 0; c < 64; ++c) {
            float2 w2 = wrow[c];
            wreg[g][c] = pk_f16(w2.x, w2.y);
        }
    }

    float bh0 = 0.f, bh1 = 0.f, bh2 = 0.f, hold = 0.f;
    if (tid < 256) {
        bh0 = bhh[j]; bh1 = bhh[256 + j]; bh2 = bhh[512 + j];
        hold = (p0 == 0) ? 0.f : hcarry[(dir * BATCH + b) * DRNN + j];
        h16[j] = (_Float16)hold;
    }
    __syncthreads();

    // prefetch gi for step 0
    float c0 = 0.f, c1 = 0.f, c2 = 0.f;
    if (tid < 256) {
        const float* p = giD + (size_t)b * G3;
        c0 = p[j]; c1 = p[256 + j]; c2 = p[512 + j];
    }

    const f16x8* hptr = (const f16x8*)&h16[half * 128];

    for (int step = 0; step < chunk; ++step) {
        const int pos = p0 + step;
        const int t = dir ? (S_LEN - 1 - pos) : pos;

        // prefetch next step's gi (latency hidden under the dot phase)
        float n0g = 0.f, n1g = 0.f, n2g = 0.f;
        if (tid < 256 && step + 1 < chunk) {
            const float* p = giD + (size_t)((step + 1) * BATCH + b) * G3;
            n0g = p[j]; n1g = p[256 + j]; n2g = p[512 + j];
        }

        // ---- dot phase: gh partials over this thread's k-half ----
        float a0 = 0.f, a1 = 0.f, a2 = 0.f;
        #pragma unroll
        for (int cc = 0; cc < 16; ++cc) {
            f16x8 h8 = hptr[cc];                      // uniform addr -> broadcast
            #pragma unroll
            for (int i = 0; i < 4; ++i) {
                f16x2 hp = { h8[2 * i], h8[2 * i + 1] };
                a0 = dot2acc(wreg[0][cc * 4 + i], hp, a0);
                a1 = dot2acc(wreg[1][cc * 4 + i], hp, a1);
                a2 = dot2acc(wreg[2][cc * 4 + i], hp, a2);
            }
        }
        if (tid >= 256) { red[0][j] = a0; red[1][j] = a1; red[2][j] = a2; }
        __syncthreads();

        // ---- gate phase (threads 0..255) ----
        if (tid < 256) {
            float sr = a0 + red[0][j] + bh0;
            float sz = a1 + red[1][j] + bh1;
            float sn = a2 + red[2][j] + bh2;
            float r  = sigm(c0 + sr);
            float z  = sigm(c1 + sz);
            float n  = tanh_f(c2 + r * sn);
            float hy = n + z * (hold - n);
            hold = hy;
            out[((size_t)t * BATCH + b) * 512 + dir * 256 + j] = hy;
            h16[j] = (_Float16)hy;
        }
        __syncthreads();
        c0 = n0g; c1 = n1g; c2 = n2g;
    }

    if (tid < 256) {
        hcarry[(dir * BATCH + b) * DRNN + j] = hold;
        if (p0 + chunk == S_LEN)    // final hidden state
            out[(size_t)S_LEN * BATCH * 512 + (dir * BATCH + b) * DRNN + j] = hold;
    }
}

// ---------------------------------------------------------------------------
extern "C" void kernel_launch(void* const* d_in, const int* in_sizes, int n_in,
                              void* d_out, int out_size, void* d_ws, size_t ws_size,
                              hipStream_t stream) {
    const float* x     = (const float*)d_in[0];
    const float* wih_f = (const float*)d_in[1];
    const float* whh_f = (const float*)d_in[2];
    const float* bih_f = (const float*)d_in[3];
    const float* bhh_f = (const float*)d_in[4];
    const float* wih_b = (const float*)d_in[5];
    const float* whh_b = (const float*)d_in[6];
    const float* bih_b = (const float*)d_in[7];
    const float* bhh_b = (const float*)d_in[8];
    float* out = (float*)d_out;

    const size_t carry_bytes = (size_t)2 * BATCH * DRNN * 4;    // 64 KB
    int chunk = 0;
    for (int c = S_LEN; c >= 16; c >>= 1) {
        size_t need = carry_bytes + (size_t)2 * c * BATCH * G3 * 4;
        if (ws_size >= need) { chunk = c; break; }
    }
    if (!chunk) return;   // ws too small — visible as unchanged output

    float* hcarry = (float*)d_ws;
    float* gi     = (float*)((char*)d_ws + carry_bytes);
    const int chunkM = chunk * BATCH;

    for (int p0 = 0; p0 < S_LEN; p0 += chunk) {
        gi_gemm<<<dim3(chunkM / 128, 6, 2), 256, 0, stream>>>(
            x, wih_f, bih_f, wih_b, bih_b, gi, p0, chunkM);
        gru_rec<<<dim3(64), 512, 0, stream>>>(
            gi, whh_f, bhh_f, whh_b, bhh_b, out, hcarry, p0, chunk);
    }
}